// Round 1
// baseline (5853.311 us; speedup 1.0000x reference)
//
#include <hip/hip_runtime.h>
#include <math.h>

#define HD 1024     // hidden size
#define BB 256      // batch
#define NCAM 15     // cameras
#define TT 60       // timesteps
#define G3 3072     // 3*H
#define KT 32       // K tile
#define LDW 36      // padded LDS row stride (floats); 36*4=144 B, 16B-aligned, bank-offset 4/row
#define NS 24       // samples per pass (3 per thread x 8 lanes)

// ---------------- grouping: per-camera sample lists ----------------
__global__ void group_kernel(const int* __restrict__ cam,
                             int* __restrict__ off, int* __restrict__ list) {
    __shared__ int cnt[NCAM];
    __shared__ int soff[NCAM + 1];
    int tid = threadIdx.x;
    if (tid < NCAM) cnt[tid] = 0;
    __syncthreads();
    int c = cam[tid];                 // tid in [0,256)
    int pos = atomicAdd(&cnt[c], 1);
    __syncthreads();
    if (tid == 0) {
        soff[0] = 0;
        for (int i = 0; i < NCAM; ++i) soff[i + 1] = soff[i] + cnt[i];
    }
    __syncthreads();
    list[soff[c] + pos] = tid;
    if (tid <= NCAM) off[tid] = soff[tid];
}

// ---------------- one-time input projection ----------------
// gi[b,g] = dot(W_ih[cam[b],g,:], x[b,:]) + b_ih[cam[b],g] + (g<2H ? b_hh[cam[b],g] : 0)
// (b_hh_n cannot be folded: it sits inside r * gh_n)
__global__ __launch_bounds__(256) void gi_kernel(
    const float* __restrict__ x, const int* __restrict__ cam,
    const float* __restrict__ W_ih, const float* __restrict__ b_ih,
    const float* __restrict__ b_hh, float* __restrict__ gi) {
    int b = blockIdx.x;
    int g = blockIdx.y * 256 + threadIdx.x;
    __shared__ __align__(16) float xs[HD];
    const float4* xg = (const float4*)(x + (size_t)b * HD);
    float4* xs4 = (float4*)xs;
    xs4[threadIdx.x] = xg[threadIdx.x];       // 256 threads * 4 floats = 1024
    __syncthreads();
    int c = cam[b];
    const float4* w4 = (const float4*)(W_ih + ((size_t)c * G3 + g) * HD);
    float acc = 0.f;
#pragma unroll 4
    for (int k = 0; k < HD / 4; ++k) {
        float4 w = w4[k];
        float4 xv = xs4[k];
        acc += w.x * xv.x + w.y * xv.y + w.z * xv.z + w.w * xv.w;
    }
    float bias = b_ih[c * G3 + g];
    if (g < 2 * HD) bias += b_hh[c * G3 + g];
    gi[(size_t)b * G3 + g] = acc + bias;
}

// ---------------- fused recurrent step ----------------
// block: camera c = blockIdx.x, j-tile of 32 = blockIdx.y
// computes gh rows {j, 1024+j, 2048+j} for <=24 samples, then GRU update.
__global__ __launch_bounds__(256) void step_kernel(
    const float* __restrict__ W_hh, const float* __restrict__ b_hh,
    const float* __restrict__ gi, const int* __restrict__ off,
    const int* __restrict__ list, const float* __restrict__ h_in,
    float* __restrict__ h_out, float* __restrict__ out, int t) {
    int c  = blockIdx.x;
    int j0 = blockIdx.y * 32;
    int tid = threadIdx.x;
    int tx = tid & 7;    // sample lane (0..7)
    int ty = tid >> 3;   // j within tile (0..31)

    __shared__ __align__(16) float wlds[96 * LDW];   // 3 gates x 32 j rows
    __shared__ __align__(16) float hlds[NS * LDW];
    __shared__ int slist[NS];

    int base = off[c];
    int nc = off[c + 1] - base;

    for (int s0 = 0; s0 < nc; s0 += NS) {
        __syncthreads();  // protect slist/hlds from previous pass
        if (tid < NS) slist[tid] = (s0 + tid < nc) ? list[base + s0 + tid] : -1;
        __syncthreads();

        float acc[3][3];  // [gate][q]
#pragma unroll
        for (int g = 0; g < 3; ++g)
#pragma unroll
            for (int q = 0; q < 3; ++q) acc[g][q] = 0.f;

        for (int k0 = 0; k0 < HD; k0 += KT) {
            // stage W: 96 rows x 32 floats, 3 float4 per thread, coalesced
#pragma unroll
            for (int i = 0; i < 3; ++i) {
                int idx = tid + 256 * i;
                int row = idx >> 3, col4 = idx & 7;
                int gate = row >> 5, jl = row & 31;
                float4 w = *(const float4*)(W_hh +
                    ((size_t)c * G3 + gate * HD + j0 + jl) * HD + k0 + col4 * 4);
                *(float4*)(wlds + row * LDW + col4 * 4) = w;
            }
            // stage h: 24 samples x 32 floats
            {
                int s = tid >> 3, col4 = tid & 7;
                if (s < NS) {
                    int b = slist[s];
                    float4 hv = make_float4(0.f, 0.f, 0.f, 0.f);
                    if (b >= 0)
                        hv = *(const float4*)(h_in + (size_t)b * HD + k0 + col4 * 4);
                    *(float4*)(hlds + s * LDW + col4 * 4) = hv;
                }
            }
            __syncthreads();
#pragma unroll
            for (int kk = 0; kk < KT; kk += 4) {
                float4 w0 = *(const float4*)(wlds + (0 * 32 + ty) * LDW + kk);
                float4 w1 = *(const float4*)(wlds + (1 * 32 + ty) * LDW + kk);
                float4 w2 = *(const float4*)(wlds + (2 * 32 + ty) * LDW + kk);
#pragma unroll
                for (int q = 0; q < 3; ++q) {
                    float4 hv = *(const float4*)(hlds + (tx + 8 * q) * LDW + kk);
                    acc[0][q] += w0.x * hv.x + w0.y * hv.y + w0.z * hv.z + w0.w * hv.w;
                    acc[1][q] += w1.x * hv.x + w1.y * hv.y + w1.z * hv.z + w1.w * hv.w;
                    acc[2][q] += w2.x * hv.x + w2.y * hv.y + w2.z * hv.z + w2.w * hv.w;
                }
            }
            __syncthreads();
        }

        // ---- GRU update epilogue ----
        int j = j0 + ty;
        float bhn = b_hh[c * G3 + 2 * HD + j];  // hidden bias for n gate (inside r*(...))
#pragma unroll
        for (int q = 0; q < 3; ++q) {
            int b = slist[tx + 8 * q];
            if (b >= 0) {
                const float* gib = gi + (size_t)b * G3;
                float gr = gib[j];
                float gz = gib[HD + j];
                float gn = gib[2 * HD + j];
                float hp = h_in[(size_t)b * HD + j];
                float r = 1.f / (1.f + expf(-(gr + acc[0][q])));
                float z = 1.f / (1.f + expf(-(gz + acc[1][q])));
                float n = tanhf(gn + r * (acc[2][q] + bhn));
                float hn = (1.f - z) * n + z * hp;
                h_out[(size_t)b * HD + j] = hn;
                out[((size_t)b * HD + j) * TT + t] = hn;
            }
        }
    }
}

extern "C" void kernel_launch(void* const* d_in, const int* in_sizes, int n_in,
                              void* d_out, int out_size, void* d_ws, size_t ws_size,
                              hipStream_t stream) {
    const float* x    = (const float*)d_in[0];
    const int*   cam  = (const int*)d_in[1];
    const float* W_ih = (const float*)d_in[2];
    const float* W_hh = (const float*)d_in[3];
    const float* b_ih = (const float*)d_in[4];
    const float* b_hh = (const float*)d_in[5];
    float* out = (float*)d_out;

    char* ws = (char*)d_ws;
    int*   off  = (int*)ws;                                  // 16 ints
    int*   list = (int*)(ws + 64);                           // 256 ints
    float* gi   = (float*)(ws + 4096);                       // 256*3072 f32 = 3 MB
    float* hA   = (float*)(ws + 4096 + (size_t)BB * G3 * 4); // 1 MB
    float* hB   = hA + (size_t)BB * HD;                      // 1 MB

    group_kernel<<<1, 256, 0, stream>>>(cam, off, list);
    gi_kernel<<<dim3(BB, G3 / 256), 256, 0, stream>>>(x, cam, W_ih, b_ih, b_hh, gi);
    hipMemsetAsync(hA, 0, (size_t)BB * HD * sizeof(float), stream);  // h0 = 0

    const float* hin = hA;
    float* hout = hB;
    for (int t = 0; t < TT; ++t) {
        step_kernel<<<dim3(NCAM, HD / 32), 256, 0, stream>>>(
            W_hh, b_hh, gi, off, list, hin, hout, out, t);
        const float* tmp = hout;
        hout = (float*)hin;
        hin = tmp;
    }
}

// Round 2
// 3876.078 us; speedup vs baseline: 1.5101x; 1.5101x over previous
//
#include <hip/hip_runtime.h>
#include <math.h>

#define HD 1024
#define BB 256
#define NCAM 15
#define TT 60
#define G3 3072
#define LDW 36      // f32 LDS stride for gi kernel
#define NS 24       // samples per pass, gi kernel
#define ASTR 72     // bf16 LDS row stride (64 data + 8 pad) -> 144 B, 16B aligned, 2-way banks (free)

typedef short bf16x8 __attribute__((ext_vector_type(8)));
typedef float f32x4 __attribute__((ext_vector_type(4)));

__device__ inline unsigned short f2bf(float f) {
    unsigned int u = __float_as_uint(f);
    u += 0x7fffu + ((u >> 16) & 1u);       // round-to-nearest-even
    return (unsigned short)(u >> 16);
}
__device__ inline float bf2f(unsigned short h) {
    return __uint_as_float(((unsigned int)h) << 16);
}
__device__ inline float sigf(float v) { return 1.f / (1.f + expf(-v)); }

// ---------------- grouping: per-camera sample lists ----------------
__global__ void group_kernel(const int* __restrict__ cam,
                             int* __restrict__ off, int* __restrict__ list) {
    __shared__ int cnt[NCAM];
    __shared__ int soff[NCAM + 1];
    int tid = threadIdx.x;
    if (tid < NCAM) cnt[tid] = 0;
    __syncthreads();
    int c = cam[tid];
    int pos = atomicAdd(&cnt[c], 1);
    __syncthreads();
    if (tid == 0) {
        soff[0] = 0;
        for (int i = 0; i < NCAM; ++i) soff[i + 1] = soff[i] + cnt[i];
    }
    __syncthreads();
    list[soff[c] + pos] = tid;
    if (tid <= NCAM) off[tid] = soff[tid];
}

// ---------------- per-camera input projection (f32, LDS-tiled) ----------------
// gi[b,R] = dot(W_ih[cam,R,:], x[b,:]) + b_ih[cam,R] + (R<2H ? b_hh[cam,R] : 0)
__global__ __launch_bounds__(256) void gi_gemm_kernel(
    const float* __restrict__ W_ih, const float* __restrict__ b_ih,
    const float* __restrict__ b_hh, const float* __restrict__ x,
    const int* __restrict__ off, const int* __restrict__ list,
    float* __restrict__ gi) {
    int c  = blockIdx.x;
    int r0 = blockIdx.y * 96;
    int tid = threadIdx.x;
    int tx = tid & 7, ty = tid >> 3;

    __shared__ __align__(16) float wlds[96 * LDW];
    __shared__ __align__(16) float hlds[NS * LDW];
    __shared__ int slist[NS];

    int base = off[c];
    int nc = off[c + 1] - base;

    for (int s0 = 0; s0 < nc; s0 += NS) {
        __syncthreads();
        if (tid < NS) slist[tid] = (s0 + tid < nc) ? list[base + s0 + tid] : -1;
        __syncthreads();

        float acc[3][3];
#pragma unroll
        for (int g = 0; g < 3; ++g)
#pragma unroll
            for (int q = 0; q < 3; ++q) acc[g][q] = 0.f;

        for (int k0 = 0; k0 < HD; k0 += 32) {
#pragma unroll
            for (int i = 0; i < 3; ++i) {
                int idx = tid + 256 * i;
                int row = idx >> 3, col4 = idx & 7;
                float4 w = *(const float4*)(W_ih +
                    ((size_t)c * G3 + r0 + row) * HD + k0 + col4 * 4);
                *(float4*)(wlds + row * LDW + col4 * 4) = w;
            }
            {
                int s = tid >> 3, col4 = tid & 7;
                if (s < NS) {
                    int b = slist[s];
                    float4 hv = make_float4(0.f, 0.f, 0.f, 0.f);
                    if (b >= 0)
                        hv = *(const float4*)(x + (size_t)b * HD + k0 + col4 * 4);
                    *(float4*)(hlds + s * LDW + col4 * 4) = hv;
                }
            }
            __syncthreads();
#pragma unroll
            for (int kk = 0; kk < 32; kk += 4) {
                float4 w0 = *(const float4*)(wlds + (0 * 32 + ty) * LDW + kk);
                float4 w1 = *(const float4*)(wlds + (1 * 32 + ty) * LDW + kk);
                float4 w2 = *(const float4*)(wlds + (2 * 32 + ty) * LDW + kk);
#pragma unroll
                for (int q = 0; q < 3; ++q) {
                    float4 hv = *(const float4*)(hlds + (tx + 8 * q) * LDW + kk);
                    acc[0][q] += w0.x * hv.x + w0.y * hv.y + w0.z * hv.z + w0.w * hv.w;
                    acc[1][q] += w1.x * hv.x + w1.y * hv.y + w1.z * hv.z + w1.w * hv.w;
                    acc[2][q] += w2.x * hv.x + w2.y * hv.y + w2.z * hv.z + w2.w * hv.w;
                }
            }
            __syncthreads();
        }
#pragma unroll
        for (int q = 0; q < 3; ++q) {
            int b = slist[tx + 8 * q];
            if (b >= 0) {
#pragma unroll
                for (int g = 0; g < 3; ++g) {
                    int R = r0 + g * 32 + ty;
                    float bias = b_ih[c * G3 + R];
                    if (R < 2 * HD) bias += b_hh[c * G3 + R];
                    gi[(size_t)b * G3 + R] = acc[g][q] + bias;
                }
            }
        }
    }
}

// ---------------- fused recurrent step: split-bf16 MFMA ----------------
// block: camera c, j-tile of 32. 128 threads = 2 waves.
// GEMM: M = 96 rows (3 gates x 32 j), N = 32 samples, K = 1024, KT = 64.
// W = Whi + Wlo (bf16 split), h = hhi + hlo; acc = Whi*hhi + Wlo*hhi + Whi*hlo.
__global__ __launch_bounds__(128) void step_mfma_kernel(
    const float* __restrict__ W_hh, const float* __restrict__ b_hh,
    const float* __restrict__ gi, const int* __restrict__ off,
    const int* __restrict__ list, const float* __restrict__ h_in,
    float* __restrict__ h_out, float* __restrict__ out, int t) {
    int c  = blockIdx.x;
    int j0 = blockIdx.y * 32;
    int tid = threadIdx.x;
    int lane = tid & 63;
    int w = tid >> 6;            // wave 0/1 -> owns jl [w*16, w*16+16)
    int l15 = lane & 15;
    int l4  = lane >> 4;

    __shared__ __align__(16) unsigned short Ahi[96 * ASTR];
    __shared__ __align__(16) unsigned short Alo[96 * ASTR];
    __shared__ __align__(16) unsigned short Bhi[32 * ASTR];
    __shared__ __align__(16) unsigned short Blo[32 * ASTR];
    __shared__ int slist[32];

    int base = off[c];
    int nc = off[c + 1] - base;

    // A staging geometry: 6 chunks/thread/plane; chunk covers 8 k of one row
    int arow[6], akc[6];
    const float* aptr[6];
#pragma unroll
    for (int i = 0; i < 6; ++i) {
        int chunk = tid + 128 * i;
        int rl = chunk >> 3, kc = chunk & 7;
        arow[i] = rl; akc[i] = kc;
        int grow = c * G3 + (rl >> 5) * HD + j0 + (rl & 31);
        aptr[i] = W_hh + (size_t)grow * HD + kc * 8;
    }
    int brow = tid >> 2, bk = (tid & 3) * 16;

    for (int s0 = 0; s0 < nc; s0 += 32) {
        __syncthreads();
        if (tid < 32) slist[tid] = (s0 + tid < nc) ? list[base + s0 + tid] : -1;
        __syncthreads();
        int myb = slist[brow];
        const float* hrow = h_in + (size_t)(myb < 0 ? 0 : myb) * HD + bk;
        int rem = nc - s0;
        int nq = (rem > 16) ? 2 : 1;

        f32x4 acc[3][2];
#pragma unroll
        for (int g = 0; g < 3; ++g)
#pragma unroll
            for (int q = 0; q < 2; ++q) acc[g][q] = (f32x4){0.f, 0.f, 0.f, 0.f};

        float4 a_pf[12], b_pf[4];
        // prefetch iter 0
#pragma unroll
        for (int i = 0; i < 6; ++i) {
            const float4* p = (const float4*)(aptr[i]);
            a_pf[2 * i] = p[0]; a_pf[2 * i + 1] = p[1];
        }
#pragma unroll
        for (int i = 0; i < 4; ++i)
            b_pf[i] = (myb >= 0) ? *(const float4*)(hrow + i * 4)
                                 : make_float4(0.f, 0.f, 0.f, 0.f);

        for (int it = 0; it < 16; ++it) {
            __syncthreads();   // previous iter's LDS consumers done
            // ---- convert + store staged tile ----
#pragma unroll
            for (int i = 0; i < 6; ++i) {
                float v[8] = {a_pf[2*i].x, a_pf[2*i].y, a_pf[2*i].z, a_pf[2*i].w,
                              a_pf[2*i+1].x, a_pf[2*i+1].y, a_pf[2*i+1].z, a_pf[2*i+1].w};
                unsigned int hp[4], lp[4];
#pragma unroll
                for (int e = 0; e < 4; ++e) {
                    unsigned short h0 = f2bf(v[2*e]),  h1 = f2bf(v[2*e+1]);
                    unsigned short g0 = f2bf(v[2*e] - bf2f(h0));
                    unsigned short g1 = f2bf(v[2*e+1] - bf2f(h1));
                    hp[e] = (unsigned)h0 | ((unsigned)h1 << 16);
                    lp[e] = (unsigned)g0 | ((unsigned)g1 << 16);
                }
                int o = arow[i] * ASTR + akc[i] * 8;
                *(uint4*)(&Ahi[o]) = make_uint4(hp[0], hp[1], hp[2], hp[3]);
                *(uint4*)(&Alo[o]) = make_uint4(lp[0], lp[1], lp[2], lp[3]);
            }
#pragma unroll
            for (int i = 0; i < 4; ++i) {
                float v[4] = {b_pf[i].x, b_pf[i].y, b_pf[i].z, b_pf[i].w};
                unsigned int hp[2], lp[2];
#pragma unroll
                for (int e = 0; e < 2; ++e) {
                    unsigned short h0 = f2bf(v[2*e]),  h1 = f2bf(v[2*e+1]);
                    unsigned short g0 = f2bf(v[2*e] - bf2f(h0));
                    unsigned short g1 = f2bf(v[2*e+1] - bf2f(h1));
                    hp[e] = (unsigned)h0 | ((unsigned)h1 << 16);
                    lp[e] = (unsigned)g0 | ((unsigned)g1 << 16);
                }
                int o = brow * ASTR + bk + i * 4;
                *(uint2*)(&Bhi[o]) = make_uint2(hp[0], hp[1]);
                *(uint2*)(&Blo[o]) = make_uint2(lp[0], lp[1]);
            }
            __syncthreads();
            // ---- prefetch next iter (overlaps MFMA below) ----
            if (it + 1 < 16) {
                int k0 = (it + 1) * 64;
#pragma unroll
                for (int i = 0; i < 6; ++i) {
                    const float4* p = (const float4*)(aptr[i] + k0);
                    a_pf[2 * i] = p[0]; a_pf[2 * i + 1] = p[1];
                }
#pragma unroll
                for (int i = 0; i < 4; ++i)
                    b_pf[i] = (myb >= 0) ? *(const float4*)(hrow + k0 + i * 4)
                                         : make_float4(0.f, 0.f, 0.f, 0.f);
            }
            // ---- compute: 2 K-tiles of 32 ----
#pragma unroll
            for (int kt = 0; kt < 2; ++kt) {
                int ko = kt * 32 + l4 * 8;
                bf16x8 bh[2], bl[2];
                bh[0] = *(const bf16x8*)(&Bhi[(0 + l15) * ASTR + ko]);
                bl[0] = *(const bf16x8*)(&Blo[(0 + l15) * ASTR + ko]);
                if (nq == 2) {
                    bh[1] = *(const bf16x8*)(&Bhi[(16 + l15) * ASTR + ko]);
                    bl[1] = *(const bf16x8*)(&Blo[(16 + l15) * ASTR + ko]);
                }
#pragma unroll
                for (int g = 0; g < 3; ++g) {
                    int ar = (g * 32 + w * 16 + l15) * ASTR + ko;
                    bf16x8 ah = *(const bf16x8*)(&Ahi[ar]);
                    bf16x8 al = *(const bf16x8*)(&Alo[ar]);
#pragma unroll
                    for (int q = 0; q < 2; ++q) {
                        if (q < nq) {
                            acc[g][q] = __builtin_amdgcn_mfma_f32_16x16x32_bf16(ah, bh[q], acc[g][q], 0, 0, 0);
                            acc[g][q] = __builtin_amdgcn_mfma_f32_16x16x32_bf16(al, bh[q], acc[g][q], 0, 0, 0);
                            acc[g][q] = __builtin_amdgcn_mfma_f32_16x16x32_bf16(ah, bl[q], acc[g][q], 0, 0, 0);
                        }
                    }
                }
            }
        }

        // ---- GRU epilogue ----
        // C/D layout: col = lane&15 (sample), row = l4*4 + reg (j within wave's 16)
        int j = j0 + w * 16 + l4 * 4;
        f32x4 bhn = *(const f32x4*)(b_hh + c * G3 + 2 * HD + j);
#pragma unroll
        for (int q = 0; q < 2; ++q) {
            if (q < nq) {
                int b = slist[q * 16 + l15];
                if (b >= 0) {
                    const float* gib = gi + (size_t)b * G3;
                    f32x4 gr = *(const f32x4*)(gib + j);
                    f32x4 gz = *(const f32x4*)(gib + HD + j);
                    f32x4 gn = *(const f32x4*)(gib + 2 * HD + j);
                    f32x4 hp = *(const f32x4*)(h_in + (size_t)b * HD + j);
                    f32x4 hn;
#pragma unroll
                    for (int e = 0; e < 4; ++e) {
                        float r = sigf(gr[e] + acc[0][q][e]);
                        float z = sigf(gz[e] + acc[1][q][e]);
                        float n = tanhf(gn[e] + r * (acc[2][q][e] + bhn[e]));
                        hn[e] = (1.f - z) * n + z * hp[e];
                        out[((size_t)(b * HD + j + e)) * TT + t] = hn[e];
                    }
                    *(f32x4*)(h_out + (size_t)b * HD + j) = hn;
                }
            }
        }
    }
}

extern "C" void kernel_launch(void* const* d_in, const int* in_sizes, int n_in,
                              void* d_out, int out_size, void* d_ws, size_t ws_size,
                              hipStream_t stream) {
    const float* x    = (const float*)d_in[0];
    const int*   cam  = (const int*)d_in[1];
    const float* W_ih = (const float*)d_in[2];
    const float* W_hh = (const float*)d_in[3];
    const float* b_ih = (const float*)d_in[4];
    const float* b_hh = (const float*)d_in[5];
    float* out = (float*)d_out;

    char* ws = (char*)d_ws;
    int*   off  = (int*)ws;
    int*   list = (int*)(ws + 64);
    float* gi   = (float*)(ws + 4096);
    float* hA   = (float*)(ws + 4096 + (size_t)BB * G3 * 4);
    float* hB   = hA + (size_t)BB * HD;

    group_kernel<<<1, 256, 0, stream>>>(cam, off, list);
    gi_gemm_kernel<<<dim3(NCAM, G3 / 96), 256, 0, stream>>>(
        W_ih, b_ih, b_hh, x, off, list, gi);
    hipMemsetAsync(hA, 0, (size_t)BB * HD * sizeof(float), stream);

    const float* hin = hA;
    float* hout = hB;
    for (int t = 0; t < TT; ++t) {
        step_mfma_kernel<<<dim3(NCAM, HD / 32), 128, 0, stream>>>(
            W_hh, b_hh, gi, off, list, hin, hout, out, t);
        const float* tmp = hout;
        hout = (float*)hin;
        hin = tmp;
    }
}

// Round 3
// 2545.564 us; speedup vs baseline: 2.2994x; 1.5227x over previous
//
#include <hip/hip_runtime.h>
#include <math.h>

#define HD 1024
#define BB 256
#define NCAM 15
#define TT 60
#define G3 3072
#define LDW 36      // f32 LDS stride for gi kernel
#define NS 24       // samples per pass, gi kernel

typedef short bf16x8 __attribute__((ext_vector_type(8)));
typedef float f32x4 __attribute__((ext_vector_type(4)));

__device__ __forceinline__ unsigned short f2bf(float f) {
    unsigned int u = __float_as_uint(f);
    u += 0x7fffu + ((u >> 16) & 1u);       // RNE
    return (unsigned short)(u >> 16);
}
__device__ __forceinline__ float bf2f(unsigned short h) {
    return __uint_as_float(((unsigned int)h) << 16);
}
__device__ __forceinline__ float sigf(float v) { return 1.f / (1.f + expf(-v)); }

// async global->LDS, 16B per lane; LDS dest = wave-uniform base + lane*16
__device__ __forceinline__ void dma16(const void* g, void* l) {
    __builtin_amdgcn_global_load_lds(
        (const __attribute__((address_space(1))) unsigned int*)g,
        (__attribute__((address_space(3))) unsigned int*)l, 16, 0, 0);
}

// ---------------- grouping ----------------
__global__ void group_kernel(const int* __restrict__ cam,
                             int* __restrict__ off, int* __restrict__ list) {
    __shared__ int cnt[NCAM];
    __shared__ int soff[NCAM + 1];
    int tid = threadIdx.x;
    if (tid < NCAM) cnt[tid] = 0;
    __syncthreads();
    int c = cam[tid];
    int pos = atomicAdd(&cnt[c], 1);
    __syncthreads();
    if (tid == 0) {
        soff[0] = 0;
        for (int i = 0; i < NCAM; ++i) soff[i + 1] = soff[i] + cnt[i];
    }
    __syncthreads();
    list[soff[c] + pos] = tid;
    if (tid <= NCAM) off[tid] = soff[tid];
}

// ---------------- per-camera input projection (f32, unchanged) ----------------
__global__ __launch_bounds__(256) void gi_gemm_kernel(
    const float* __restrict__ W_ih, const float* __restrict__ b_ih,
    const float* __restrict__ b_hh, const float* __restrict__ x,
    const int* __restrict__ off, const int* __restrict__ list,
    float* __restrict__ gi) {
    int c  = blockIdx.x;
    int r0 = blockIdx.y * 96;
    int tid = threadIdx.x;
    int tx = tid & 7, ty = tid >> 3;

    __shared__ __align__(16) float wlds[96 * LDW];
    __shared__ __align__(16) float hlds[NS * LDW];
    __shared__ int slist[NS];

    int base = off[c];
    int nc = off[c + 1] - base;

    for (int s0 = 0; s0 < nc; s0 += NS) {
        __syncthreads();
        if (tid < NS) slist[tid] = (s0 + tid < nc) ? list[base + s0 + tid] : -1;
        __syncthreads();

        float acc[3][3];
#pragma unroll
        for (int g = 0; g < 3; ++g)
#pragma unroll
            for (int q = 0; q < 3; ++q) acc[g][q] = 0.f;

        for (int k0 = 0; k0 < HD; k0 += 32) {
#pragma unroll
            for (int i = 0; i < 3; ++i) {
                int idx = tid + 256 * i;
                int row = idx >> 3, col4 = idx & 7;
                float4 w = *(const float4*)(W_ih +
                    ((size_t)c * G3 + r0 + row) * HD + k0 + col4 * 4);
                *(float4*)(wlds + row * LDW + col4 * 4) = w;
            }
            {
                int s = tid >> 3, col4 = tid & 7;
                if (s < NS) {
                    int b = slist[s];
                    float4 hv = make_float4(0.f, 0.f, 0.f, 0.f);
                    if (b >= 0)
                        hv = *(const float4*)(x + (size_t)b * HD + k0 + col4 * 4);
                    *(float4*)(hlds + s * LDW + col4 * 4) = hv;
                }
            }
            __syncthreads();
#pragma unroll
            for (int kk = 0; kk < 32; kk += 4) {
                float4 w0 = *(const float4*)(wlds + (0 * 32 + ty) * LDW + kk);
                float4 w1 = *(const float4*)(wlds + (1 * 32 + ty) * LDW + kk);
                float4 w2 = *(const float4*)(wlds + (2 * 32 + ty) * LDW + kk);
#pragma unroll
                for (int q = 0; q < 3; ++q) {
                    float4 hv = *(const float4*)(hlds + (tx + 8 * q) * LDW + kk);
                    acc[0][q] += w0.x * hv.x + w0.y * hv.y + w0.z * hv.z + w0.w * hv.w;
                    acc[1][q] += w1.x * hv.x + w1.y * hv.y + w1.z * hv.z + w1.w * hv.w;
                    acc[2][q] += w2.x * hv.x + w2.y * hv.y + w2.z * hv.z + w2.w * hv.w;
                }
            }
            __syncthreads();
        }
#pragma unroll
        for (int q = 0; q < 3; ++q) {
            int b = slist[tx + 8 * q];
            if (b >= 0) {
#pragma unroll
                for (int g = 0; g < 3; ++g) {
                    int R = r0 + g * 32 + ty;
                    float bias = b_ih[c * G3 + R];
                    if (R < 2 * HD) bias += b_hh[c * G3 + R];
                    gi[(size_t)b * G3 + R] = acc[g][q] + bias;
                }
            }
        }
    }
}

// ---------------- W_hh -> split-bf16 DMA-image prep ----------------
// Image layout per (cam, jtile, iter): 1536 chunks of 16B, exactly the order
// the step kernel's DMA deposits: hi plane (768 chunks: r*8 + kc'), then lo.
// chunk (r, kc') holds global k = it*64 + (kc' ^ (r&7))*8 .. +8 (XOR swizzle).
__global__ __launch_bounds__(256) void prep_kernel(
    const float* __restrict__ W_hh, unsigned short* __restrict__ Wimg) {
    int c = blockIdx.z, jt = blockIdx.y;
    int lin = blockIdx.x * 256 + threadIdx.x;   // [0, 12288) = 16 iters * 768 chunks
    int it  = lin / 768;
    int rem = lin - it * 768;
    int r = rem >> 3, kcp = rem & 7;
    int gate = r >> 5, jl = r & 31;
    int kc = kcp ^ (r & 7);
    int k = it * 64 + kc * 8;
    const float* src = W_hh + ((size_t)c * G3 + gate * HD + jt * 32 + jl) * HD + k;
    float4 v0 = *(const float4*)src;
    float4 v1 = *(const float4*)(src + 4);
    float v[8] = {v0.x, v0.y, v0.z, v0.w, v1.x, v1.y, v1.z, v1.w};
    unsigned int hp[4], lp[4];
#pragma unroll
    for (int e = 0; e < 4; ++e) {
        unsigned short h0 = f2bf(v[2 * e]), h1 = f2bf(v[2 * e + 1]);
        unsigned short g0 = f2bf(v[2 * e] - bf2f(h0));
        unsigned short g1 = f2bf(v[2 * e + 1] - bf2f(h1));
        hp[e] = (unsigned)h0 | ((unsigned)h1 << 16);
        lp[e] = (unsigned)g0 | ((unsigned)g1 << 16);
    }
    unsigned short* dhi = Wimg + ((size_t)(c * 32 + jt) * 16 + it) * 12288 + r * 64 + kcp * 8;
    *(uint4*)dhi = make_uint4(hp[0], hp[1], hp[2], hp[3]);
    *(uint4*)(dhi + 6144) = make_uint4(lp[0], lp[1], lp[2], lp[3]);
}

// ---------------- fused recurrent step: DMA staging + MFMA ----------------
__global__ __launch_bounds__(128) void step_dma_kernel(
    const unsigned short* __restrict__ Wimg, const float* __restrict__ b_hh,
    const float* __restrict__ gi, const int* __restrict__ off,
    const int* __restrict__ list, const float* __restrict__ h_in,
    const unsigned short* __restrict__ hhi_in, const unsigned short* __restrict__ hlo_in,
    const unsigned short* __restrict__ hzero,
    float* __restrict__ h_out, unsigned short* __restrict__ hhi_out,
    unsigned short* __restrict__ hlo_out, float* __restrict__ out, int t) {
    int c  = blockIdx.x;
    int jt = blockIdx.y;
    int j0 = jt * 32;
    int tid = threadIdx.x;
    int lane = tid & 63;
    int w = tid >> 6;
    int l15 = lane & 15;
    int l4  = lane >> 4;

    __shared__ __align__(16) unsigned short Ash[12288];  // 2 planes x 96 x 64
    __shared__ __align__(16) unsigned short Bsh[4096];   // 2 planes x 32 x 64
    __shared__ int slist[32];

    const unsigned short* wbase = Wimg + (size_t)(c * 32 + jt) * 16 * 12288;
    int base = off[c];
    int nc = off[c + 1] - base;

    // B DMA decode (4 insts x 128 threads = 512 chunks = 2 planes x 32 s x 8 kc')
    int bs[4], bkc[4], bpl[4];
#pragma unroll
    for (int i = 0; i < 4; ++i) {
        int p = i * 128 + tid;
        bpl[i] = p >> 8;
        bs[i]  = (p >> 3) & 31;
        bkc[i] = (p & 7) ^ (bs[i] & 7);   // global k-chunk after inverse swizzle
    }

    for (int s0 = 0; s0 < nc; s0 += 32) {
        __syncthreads();
        if (tid < 32) slist[tid] = (s0 + tid < nc) ? list[base + s0 + tid] : -1;
        __syncthreads();
        int rem = nc - s0;
        int nq = (rem > 16) ? 2 : 1;

        const unsigned short* bg[4];
        int bstep[4];
#pragma unroll
        for (int i = 0; i < 4; ++i) {
            int b = slist[bs[i]];
            const unsigned short* hp = bpl[i] ? hlo_in : hhi_in;
            bg[i] = (b >= 0) ? hp + (size_t)b * HD + bkc[i] * 8 : hzero;
            bstep[i] = (b >= 0) ? 1 : 0;
        }

        f32x4 acc[3][2];
#pragma unroll
        for (int g = 0; g < 3; ++g)
#pragma unroll
            for (int q = 0; q < 2; ++q) acc[g][q] = (f32x4){0.f, 0.f, 0.f, 0.f};

        for (int it = 0; it < 16; ++it) {
            const char* asrc = (const char*)(wbase + (size_t)it * 12288);
            // A: 12 DMA insts, purely sequential 24576 B
#pragma unroll
            for (int i = 0; i < 12; ++i)
                dma16(asrc + (i * 128 + tid) * 16,
                      (char*)Ash + (i * 128 + (w << 6)) * 16);
            // B: 4 DMA insts, per-lane gather from h planes
            int k0 = it * 64;
#pragma unroll
            for (int i = 0; i < 4; ++i)
                dma16(bg[i] + k0 * bstep[i],
                      (char*)Bsh + (i * 128 + (w << 6)) * 16);
            __syncthreads();

#pragma unroll
            for (int kt = 0; kt < 2; ++kt) {
                int kc = kt * 4 + l4;
                bf16x8 bh[2], bl[2];
#pragma unroll
                for (int q = 0; q < 2; ++q) {
                    if (q < nq) {
                        int s = q * 16 + l15;
                        int boff = s * 64 + ((kc ^ (s & 7)) * 8);
                        bh[q] = *(const bf16x8*)(&Bsh[boff]);
                        bl[q] = *(const bf16x8*)(&Bsh[2048 + boff]);
                    }
                }
#pragma unroll
                for (int g = 0; g < 3; ++g) {
                    int r = g * 32 + w * 16 + l15;
                    int aoff = r * 64 + ((kc ^ (r & 7)) * 8);
                    bf16x8 ah = *(const bf16x8*)(&Ash[aoff]);
                    bf16x8 al = *(const bf16x8*)(&Ash[6144 + aoff]);
#pragma unroll
                    for (int q = 0; q < 2; ++q) {
                        if (q < nq) {
                            acc[g][q] = __builtin_amdgcn_mfma_f32_16x16x32_bf16(ah, bh[q], acc[g][q], 0, 0, 0);
                            acc[g][q] = __builtin_amdgcn_mfma_f32_16x16x32_bf16(al, bh[q], acc[g][q], 0, 0, 0);
                            acc[g][q] = __builtin_amdgcn_mfma_f32_16x16x32_bf16(ah, bl[q], acc[g][q], 0, 0, 0);
                        }
                    }
                }
            }
            __syncthreads();
        }

        // ---- GRU epilogue ----
        int j = j0 + w * 16 + l4 * 4;
        f32x4 bhn = *(const f32x4*)(b_hh + c * G3 + 2 * HD + j);
#pragma unroll
        for (int q = 0; q < 2; ++q) {
            if (q < nq) {
                int b = slist[q * 16 + l15];
                if (b >= 0) {
                    const float* gib = gi + (size_t)b * G3;
                    f32x4 gr = *(const f32x4*)(gib + j);
                    f32x4 gz = *(const f32x4*)(gib + HD + j);
                    f32x4 gn = *(const f32x4*)(gib + 2 * HD + j);
                    f32x4 hp = *(const f32x4*)(h_in + (size_t)b * HD + j);
                    f32x4 hn;
                    unsigned int hiw[2], low[2];
#pragma unroll
                    for (int e = 0; e < 4; ++e) {
                        float r = sigf(gr[e] + acc[0][q][e]);
                        float z = sigf(gz[e] + acc[1][q][e]);
                        float n = tanhf(gn[e] + r * (acc[2][q][e] + bhn[e]));
                        hn[e] = (1.f - z) * n + z * hp[e];
                        out[((size_t)(b * HD + j + e)) * TT + t] = hn[e];
                    }
#pragma unroll
                    for (int e = 0; e < 2; ++e) {
                        unsigned short h0 = f2bf(hn[2 * e]), h1 = f2bf(hn[2 * e + 1]);
                        unsigned short g0 = f2bf(hn[2 * e] - bf2f(h0));
                        unsigned short g1 = f2bf(hn[2 * e + 1] - bf2f(h1));
                        hiw[e] = (unsigned)h0 | ((unsigned)h1 << 16);
                        low[e] = (unsigned)g0 | ((unsigned)g1 << 16);
                    }
                    *(f32x4*)(h_out + (size_t)b * HD + j) = hn;
                    *(uint2*)(hhi_out + (size_t)b * HD + j) = make_uint2(hiw[0], hiw[1]);
                    *(uint2*)(hlo_out + (size_t)b * HD + j) = make_uint2(low[0], low[1]);
                }
            }
        }
    }
}

extern "C" void kernel_launch(void* const* d_in, const int* in_sizes, int n_in,
                              void* d_out, int out_size, void* d_ws, size_t ws_size,
                              hipStream_t stream) {
    const float* x    = (const float*)d_in[0];
    const int*   cam  = (const int*)d_in[1];
    const float* W_ih = (const float*)d_in[2];
    const float* W_hh = (const float*)d_in[3];
    const float* b_ih = (const float*)d_in[4];
    const float* b_hh = (const float*)d_in[5];
    float* out = (float*)d_out;

    char* ws = (char*)d_ws;
    int*   off   = (int*)ws;                          // 64 B
    int*   list  = (int*)(ws + 64);                   // 1 KB
    unsigned short* hzero = (unsigned short*)(ws + 2048);  // 2 KB zeros
    float* gi    = (float*)(ws + 4096);               // 3 MB
    float* hA    = (float*)(ws + 3149824);            // 1 MB
    float* hB    = (float*)(ws + 4198400);            // 1 MB
    unsigned short* hhiA = (unsigned short*)(ws + 5246976);  // 512 KB
    unsigned short* hloA = (unsigned short*)(ws + 5771264);  // 512 KB
    unsigned short* hhiB = (unsigned short*)(ws + 6295552);  // 512 KB
    unsigned short* hloB = (unsigned short*)(ws + 6819840);  // 512 KB
    unsigned short* Wimg = (unsigned short*)(ws + 7344128);  // 188.7 MB

    group_kernel<<<1, 256, 0, stream>>>(cam, off, list);
    gi_gemm_kernel<<<dim3(NCAM, G3 / 96), 256, 0, stream>>>(
        W_ih, b_ih, b_hh, x, off, list, gi);
    prep_kernel<<<dim3(48, 32, NCAM), 256, 0, stream>>>(W_hh, Wimg);
    hipMemsetAsync(hzero, 0, 2048, stream);
    hipMemsetAsync(hA, 0, (size_t)BB * HD * sizeof(float), stream);
    hipMemsetAsync(hhiA, 0, (size_t)BB * HD * 2 * sizeof(short), stream); // hhiA+hloA

    const float* hin = hA;            float* hout = hB;
    const unsigned short* hhi_in = hhiA;  unsigned short* hhi_out = hhiB;
    const unsigned short* hlo_in = hloA;  unsigned short* hlo_out = hloB;
    for (int t = 0; t < TT; ++t) {
        step_dma_kernel<<<dim3(NCAM, HD / 32), 128, 0, stream>>>(
            Wimg, b_hh, gi, off, list, hin, hhi_in, hlo_in, hzero,
            hout, hhi_out, hlo_out, out, t);
        { const float* tmp = hin; hin = hout; hout = (float*)tmp; }
        { const unsigned short* tmp = hhi_in; hhi_in = hhi_out; hhi_out = (unsigned short*)tmp; }
        { const unsigned short* tmp = hlo_in; hlo_in = hlo_out; hlo_out = (unsigned short*)tmp; }
    }
}